// Round 4
// baseline (308.978 us; speedup 1.0000x reference)
//
#include <hip/hip_runtime.h>
#include <hip/hip_bf16.h>
#include <math.h>

#define Bb 8
#define Nn 96
#define Dd 256
#define BN (Bb*Nn)      /* 768 */
#define MT (BN*Nn)      /* 73728 edge rows */
#define MB 32           /* rows per dk_attn block */
#define NMB 3           /* M-blocks per bn */
#define PI_OVER_CUTOFF 0.62831853071795864769f  /* pi/5 */

#define WT_BLOCKS   512
#define QKV_BLOCKS  ((BN / 2) * 3)     /* 1152 */

typedef short short8 __attribute__((ext_vector_type(8)));
typedef float f32x4  __attribute__((ext_vector_type(4)));

// fast silu: v_exp_f32 + v_rcp_f32 are ~1ulp; inputs already bf16-quantized.
__device__ __forceinline__ float silu_f(float x){
    return x * __builtin_amdgcn_rcpf(1.0f + __expf(-x));
}

__device__ __forceinline__ short f2bf(float f){
    __hip_bfloat16 h = __float2bfloat16(f);
    return __builtin_bit_cast(short, h);
}
__device__ __forceinline__ float bf2f(unsigned short u){
    union { unsigned uu; float ff; } a; a.uu = ((unsigned)u) << 16; return a.ff;
}
// pack two fp32 -> two bf16 (round-half-up).
__device__ __forceinline__ unsigned pkbf(float lo, float hi){
    unsigned a = __builtin_bit_cast(unsigned, lo) + 0x8000u;
    unsigned b = __builtin_bit_cast(unsigned, hi) + 0x8000u;
    return __builtin_amdgcn_perm(b, a, 0x07060302);  // (b[31:16]<<16)|a[31:16]
}

// ---------------- Kernel 1: setup = wt (W^T bf16) + qkv ----------------
__global__ __launch_bounds__(256) void setup_kernel(
    const float* __restrict__ Wdk, const float* __restrict__ Wea,
    short* __restrict__ Wtdk, short* __restrict__ Wtea,
    const float* __restrict__ x,
    const float* __restrict__ Wq, const float* __restrict__ bq,
    const float* __restrict__ Wk, const float* __restrict__ bk,
    const float* __restrict__ Wv, const float* __restrict__ bv,
    float* __restrict__ qo, float* __restrict__ ko, float* __restrict__ vo)
{
    const int blk = blockIdx.x;
    const int tid = threadIdx.x;

    if (blk < WT_BLOCKS) {
        // ---- Wt = bf16(W^T) ----
        const int o   = blk * 256 + tid;
        const int sel = o >> 16;
        const int r   = o & 65535;
        const int n   = r >> 8, k = r & 255;
        const float* src = sel ? Wea : Wdk;
        short*       dst = sel ? Wtea : Wtdk;
        dst[r] = f2bf(src[k * 256 + n]);
        return;
    }

    // ---- qkv: 2 rows, 1 matrix per block ----
    __shared__ float xs[2][Dd];
    const int idx = blk - WT_BLOCKS;
    const int sel = idx % 3;
    const int r0  = (idx / 3) * 2;
    const float* W  = sel == 0 ? Wq : (sel == 1 ? Wk : Wv);
    const float* bb = sel == 0 ? bq : (sel == 1 ? bk : bv);
    float*       ou = sel == 0 ? qo : (sel == 1 ? ko : vo);

    #pragma unroll
    for (int i = 0; i < 2; ++i) xs[i][tid] = x[(size_t)(r0 + i) * Dd + tid];
    __syncthreads();

    float a0, a1;
    a0 = a1 = bb[tid];
    for (int k4 = 0; k4 < 64; ++k4) {
        const float w0 = W[(size_t)(k4 * 4 + 0) * Dd + tid];
        const float w1 = W[(size_t)(k4 * 4 + 1) * Dd + tid];
        const float w2 = W[(size_t)(k4 * 4 + 2) * Dd + tid];
        const float w3 = W[(size_t)(k4 * 4 + 3) * Dd + tid];
        const float4 e0 = *(const float4*)&xs[0][k4 * 4];
        const float4 e1 = *(const float4*)&xs[1][k4 * 4];
        a0 = fmaf(e0.x, w0, fmaf(e0.y, w1, fmaf(e0.z, w2, fmaf(e0.w, w3, a0))));
        a1 = fmaf(e1.x, w0, fmaf(e1.y, w1, fmaf(e1.z, w2, fmaf(e1.w, w3, a1))));
    }
    ou[(size_t)r0 * Dd + tid]       = a0;
    ou[(size_t)(r0 + 1) * Dd + tid] = a1;
}

// ---------------- Kernel 2: M-split fused dk-GEMM + attention + ea-GEMM ----------------
// Grid = 2304: block L -> batch b = L&7 (== XCD under round-robin dispatch), bn, mb.
// 512 thr = 8 waves; wave w owns cols [w*32,+32) = head w. MB=32 rows, K=256.
// Sequential GEMMs over the same LDS tiles (acc 16 + acce 16 regs live together).
// 3 blocks/CU via __launch_bounds__(512,6): VGPR cap 85 for 24 waves/CU.
__global__ __launch_bounds__(512, 6) void dk_attn_kernel(
    const float* __restrict__ edge,
    const short* __restrict__ Wt, const short* __restrict__ Wte,
    const float* __restrict__ bdk, const float* __restrict__ bea,
    const float* __restrict__ q, const float* __restrict__ kmat, const float* __restrict__ vmat,
    const int* __restrict__ mask, const float* __restrict__ dist, const float* __restrict__ vec,
    float* __restrict__ attn_part, float* __restrict__ t_part,
    unsigned short* __restrict__ eab)
{
    __shared__ short As[2 * MB * 128];   // 16 KB
    __shared__ float scl[MB];
    __shared__ float vcs[MB][3];

    const int L    = blockIdx.x;
    const int b    = L & 7;              // XCD slot == batch
    const int rest = L >> 3;             // 0..287
    const int bn   = b * Nn + rest / NMB;
    const int mb   = rest % NMB;
    const int m0   = mb * MB;
    const int tid  = threadIdx.x;
    const int lane = tid & 63;
    const int w    = tid >> 6;
    const int l15  = lane & 15;
    const int lq   = lane >> 4;

    if (tid < MB) {
        const int   mm = mask[(size_t)bn * Nn + m0 + tid];
        const float di = dist[(size_t)bn * Nn + m0 + tid];
        const float s  = (di < 5.0f) ? 0.5f * (__cosf(di * PI_OVER_CUTOFF) + 1.0f) : 0.0f;
        scl[tid] = mm ? 0.0f : s;
    }
    if (tid < MB * 3)
        (&vcs[0][0])[tid] = vec[((size_t)bn * Nn + m0) * 3 + tid];

    const int dj0 = w * 32 + l15, dj1 = dj0 + 16;
    const float qd0 = q[(size_t)bn * Dd + dj0], qd1 = q[(size_t)bn * Dd + dj1];
    const float bv0 = bdk[dj0], bv1 = bdk[dj1];
    const float be0 = bea[dj0], be1 = bea[dj1];

    const float* ebase = edge + ((size_t)bn * Nn + m0) * Dd;
    const int srow = lq;           // 0..3: row within this wave's 4-row chunk
    const int cs   = l15;          // stored segment

    // ---- stage MB x 256 fp32 -> bf16 LDS (wave w owns rows [w*4, w*4+4) per chunk) ----
    {
        const int r    = w * 4 + srow;
        const int gseg = cs ^ (r & 7);
        float4 fa0, fb0, fa1, fb1;
        {
            const float* s0 = ebase + (size_t)r * Dd + gseg * 8;
            const float* s1 = ebase + (size_t)r * Dd + 128 + gseg * 8;
            fa0 = *(const float4*)s0;  fb0 = *(const float4*)(s0 + 4);
            fa1 = *(const float4*)s1;  fb1 = *(const float4*)(s1 + 4);
        }
        uint4 p0, p1;
        p0.x = pkbf(fa0.x, fa0.y); p0.y = pkbf(fa0.z, fa0.w);
        p0.z = pkbf(fb0.x, fb0.y); p0.w = pkbf(fb0.z, fb0.w);
        p1.x = pkbf(fa1.x, fa1.y); p1.y = pkbf(fa1.z, fa1.w);
        p1.z = pkbf(fb1.x, fb1.y); p1.w = pkbf(fb1.z, fb1.w);
        *(uint4*)&As[              w * 512 + lane * 8] = p0;
        *(uint4*)&As[MB * 128 +    w * 512 + lane * 8] = p1;
    }
    __syncthreads();

    f32x4 acc[2][2], acce[2][2];
    #pragma unroll
    for (int i = 0; i < 2; ++i) {
        acc[i][0]  = (f32x4){0.f,0.f,0.f,0.f}; acc[i][1]  = (f32x4){0.f,0.f,0.f,0.f};
        acce[i][0] = (f32x4){0.f,0.f,0.f,0.f}; acce[i][1] = (f32x4){0.f,0.f,0.f,0.f};
    }

    // ---- GEMM 1: dk = edge @ Wdk ----
    #pragma unroll
    for (int kt = 0; kt < 2; ++kt) {
        short8 bf0[4], bf1[4];
        #pragma unroll
        for (int s = 0; s < 4; ++s) {
            bf0[s] = *(const short8*)(Wt + (size_t)dj0 * 256 + kt * 128 + s * 32 + lq * 8);
            bf1[s] = *(const short8*)(Wt + (size_t)dj1 * 256 + kt * 128 + s * 32 + lq * 8);
        }
        #pragma unroll
        for (int s = 0; s < 4; ++s) {
            #pragma unroll
            for (int i = 0; i < 2; ++i) {
                const int row = i * 16 + l15;
                const int pos = (s * 4 + lq) ^ (row & 7);
                const short8 af = *(const short8*)&As[kt * (MB*128) + row * 128 + pos * 8];
                acc[i][0] = __builtin_amdgcn_mfma_f32_16x16x32_bf16(af, bf0[s], acc[i][0], 0, 0, 0);
                acc[i][1] = __builtin_amdgcn_mfma_f32_16x16x32_bf16(af, bf1[s], acc[i][1], 0, 0, 0);
            }
        }
    }
    // ---- GEMM 2: ea = edge @ Wea (same LDS tiles, fresh B frags) ----
    #pragma unroll
    for (int kt = 0; kt < 2; ++kt) {
        short8 bf0[4], bf1[4];
        #pragma unroll
        for (int s = 0; s < 4; ++s) {
            bf0[s] = *(const short8*)(Wte + (size_t)dj0 * 256 + kt * 128 + s * 32 + lq * 8);
            bf1[s] = *(const short8*)(Wte + (size_t)dj1 * 256 + kt * 128 + s * 32 + lq * 8);
        }
        #pragma unroll
        for (int s = 0; s < 4; ++s) {
            #pragma unroll
            for (int i = 0; i < 2; ++i) {
                const int row = i * 16 + l15;
                const int pos = (s * 4 + lq) ^ (row & 7);
                const short8 af = *(const short8*)&As[kt * (MB*128) + row * 128 + pos * 8];
                acce[i][0] = __builtin_amdgcn_mfma_f32_16x16x32_bf16(af, bf0[s], acce[i][0], 0, 0, 0);
                acce[i][1] = __builtin_amdgcn_mfma_f32_16x16x32_bf16(af, bf1[s], acce[i][1], 0, 0, 0);
            }
        }
    }

    // ---- ea epilogue first: stores drain under the attn VALU phase ----
    #pragma unroll
    for (int i = 0; i < 2; ++i) {
        #pragma unroll
        for (int rr = 0; rr < 4; ++rr) {
            const int ml = i * 16 + lq * 4 + rr;
            const size_t er = ((size_t)bn * Nn + m0 + ml) * Dd;
            eab[er + dj0] = (unsigned short)f2bf(silu_f(acce[i][0][rr] + be0));
            eab[er + dj1] = (unsigned short)f2bf(silu_f(acce[i][1][rr] + be1));
        }
    }

    // ---- attention epilogue (per-head: quarter-wave = 16 d's, head = wave) ----
    float attn0 = 0.f, attn1 = 0.f;
    float t00=0.f, t01=0.f, t02=0.f, t10=0.f, t11=0.f, t12=0.f;

    #pragma unroll
    for (int i = 0; i < 2; ++i) {
        #pragma unroll
        for (int rr = 0; rr < 4; ++rr) {
            const int ml = i * 16 + lq * 4 + rr;
            const size_t krow = ((size_t)(b * Nn + m0 + ml)) << 8;
            const float k0 = kmat[krow + dj0], k1 = kmat[krow + dj1];
            const float v0 = vmat[krow + dj0], v1 = vmat[krow + dj1];
            float pr = silu_f(acc[i][0][rr] + bv0) * k0 * qd0
                     + silu_f(acc[i][1][rr] + bv1) * k1 * qd1;
            #pragma unroll
            for (int off = 8; off; off >>= 1)
                pr += __shfl_xor(pr, off, 16);
            const float p = silu_f(pr) * scl[ml];
            const float pv0 = p * v0, pv1 = p * v1;
            attn0 += pv0; attn1 += pv1;
            const float c0 = vcs[ml][0], c1 = vcs[ml][1], c2 = vcs[ml][2];
            t00 = fmaf(c0, pv0, t00); t01 = fmaf(c1, pv0, t01); t02 = fmaf(c2, pv0, t02);
            t10 = fmaf(c0, pv1, t10); t11 = fmaf(c1, pv1, t11); t12 = fmaf(c2, pv1, t12);
        }
    }

    attn0 += __shfl_xor(attn0, 16, 64); attn0 += __shfl_xor(attn0, 32, 64);
    attn1 += __shfl_xor(attn1, 16, 64); attn1 += __shfl_xor(attn1, 32, 64);
    t00 += __shfl_xor(t00, 16, 64); t00 += __shfl_xor(t00, 32, 64);
    t01 += __shfl_xor(t01, 16, 64); t01 += __shfl_xor(t01, 32, 64);
    t02 += __shfl_xor(t02, 16, 64); t02 += __shfl_xor(t02, 32, 64);
    t10 += __shfl_xor(t10, 16, 64); t10 += __shfl_xor(t10, 32, 64);
    t11 += __shfl_xor(t11, 16, 64); t11 += __shfl_xor(t11, 32, 64);
    t12 += __shfl_xor(t12, 16, 64); t12 += __shfl_xor(t12, 32, 64);

    if (lq == 0) {
        const size_t pb = ((size_t)mb * BN + bn);
        attn_part[pb * Dd + dj0] = attn0;
        attn_part[pb * Dd + dj1] = attn1;
        t_part[(pb * 3 + 0) * Dd + dj0] = t00;
        t_part[(pb * 3 + 1) * Dd + dj0] = t01;
        t_part[(pb * 3 + 2) * Dd + dj0] = t02;
        t_part[(pb * 3 + 0) * Dd + dj1] = t10;
        t_part[(pb * 3 + 1) * Dd + dj1] = t11;
        t_part[(pb * 3 + 2) * Dd + dj1] = t12;
    }
}

// ---------------- Kernel 3: combine partials + sv + du + w = du@Wdih ----------------
__global__ __launch_bounds__(256) void du_kernel(
    const float* __restrict__ t_part, const float* __restrict__ attn_part,
    const int* __restrict__ mask, const float* __restrict__ vec,
    const float* __restrict__ Wdu, const float* __restrict__ bdu,
    const float* __restrict__ Wdih,
    float* __restrict__ attn_out,
    float* __restrict__ wsv, unsigned short* __restrict__ wtp)
{
    const int bn  = blockIdx.x;
    const int tid = threadIdx.x;
    __shared__ float ts[3][Dd];
    __shared__ float dus[3][Dd];
    __shared__ float svs[3];

    #pragma unroll
    for (int j = 0; j < 3; ++j) {
        float s = 0.f;
        #pragma unroll
        for (int mb = 0; mb < NMB; ++mb)
            s += t_part[(((size_t)mb * BN + bn) * 3 + j) * Dd + tid];
        ts[j][tid] = s;
    }
    {
        float a = 0.f;
        #pragma unroll
        for (int mb = 0; mb < NMB; ++mb)
            a += attn_part[((size_t)mb * BN + bn) * Dd + tid];
        attn_out[(size_t)bn * Dd + tid] = a;
    }

    if (tid < 192) {
        const int c  = tid >> 6;
        const int ln = tid & 63;
        float s = 0.0f;
        for (int m = ln; m < Nn; m += 64)
            if (!mask[(size_t)bn * Nn + m]) s += vec[((size_t)bn * Nn + m) * 3 + c];
        #pragma unroll
        for (int off = 32; off; off >>= 1) s += __shfl_xor(s, off, 64);
        if (ln == 0) svs[c] = s;
    }
    __syncthreads();

    float du[3];
    const float bd = bdu[tid];
    #pragma unroll
    for (int j = 0; j < 3; ++j) du[j] = svs[j] * bd;

    for (int k4 = 0; k4 < 64; ++k4) {
        const float w0 = Wdu[(size_t)(k4 * 4 + 0) * Dd + tid];
        const float w1 = Wdu[(size_t)(k4 * 4 + 1) * Dd + tid];
        const float w2 = Wdu[(size_t)(k4 * 4 + 2) * Dd + tid];
        const float w3 = Wdu[(size_t)(k4 * 4 + 3) * Dd + tid];
        #pragma unroll
        for (int j = 0; j < 3; ++j) {
            const float4 e = *(const float4*)&ts[j][k4 * 4];
            du[j] = fmaf(e.x, w0, fmaf(e.y, w1, fmaf(e.z, w2, fmaf(e.w, w3, du[j]))));
        }
    }
    #pragma unroll
    for (int j = 0; j < 3; ++j) dus[j][tid] = du[j];
    __syncthreads();

    float as[3] = {0.f, 0.f, 0.f}, at[3] = {0.f, 0.f, 0.f};

    for (int k4 = 0; k4 < 64; ++k4) {
        const float s0 = Wdih[(size_t)(k4 * 4 + 0) * 512 + tid];
        const float s1 = Wdih[(size_t)(k4 * 4 + 1) * 512 + tid];
        const float s2 = Wdih[(size_t)(k4 * 4 + 2) * 512 + tid];
        const float s3 = Wdih[(size_t)(k4 * 4 + 3) * 512 + tid];
        const float u0 = Wdih[(size_t)(k4 * 4 + 0) * 512 + 256 + tid];
        const float u1 = Wdih[(size_t)(k4 * 4 + 1) * 512 + 256 + tid];
        const float u2 = Wdih[(size_t)(k4 * 4 + 2) * 512 + 256 + tid];
        const float u3 = Wdih[(size_t)(k4 * 4 + 3) * 512 + 256 + tid];
        #pragma unroll
        for (int j = 0; j < 3; ++j) {
            const float4 e = *(const float4*)&dus[j][k4 * 4];
            as[j] = fmaf(e.x, s0, fmaf(e.y, s1, fmaf(e.z, s2, fmaf(e.w, s3, as[j]))));
            at[j] = fmaf(e.x, u0, fmaf(e.y, u1, fmaf(e.z, u2, fmaf(e.w, u3, at[j]))));
        }
    }
    #pragma unroll
    for (int j = 0; j < 3; ++j)
        wsv[((size_t)bn * 3 + j) * Dd + tid] = as[j];
    ushort4 pk;
    pk.x = (unsigned short)f2bf(at[0]);
    pk.y = (unsigned short)f2bf(at[1]);
    pk.z = (unsigned short)f2bf(at[2]);
    pk.w = 0;
    *(ushort4*)(wtp + ((size_t)bn * Dd + tid) * 4) = pk;
}

// ---------------- Kernel 4: ipe = ea * sum_c ws.wt  (streaming, d-pair vectorized) ----------------
__global__ __launch_bounds__(512) void ipe_kernel(
    const unsigned short* __restrict__ eab,
    const float* __restrict__ wsv, const unsigned short* __restrict__ wtp,
    float* __restrict__ ipe)
{
    const int bid = blockIdx.x;
    const int bn  = (bid & 7) * Nn + (bid >> 3);
    const int b   = bid & 7;
    const int tid = threadIdx.x;
    const int d2  = tid & 127;          // d-pair index
    const int mg  = tid >> 7;           // 0..3, 24 m each
    const int d0  = d2 * 2;

    const float w00 = wsv[((size_t)bn * 3 + 0) * Dd + d0];
    const float w01 = wsv[((size_t)bn * 3 + 1) * Dd + d0];
    const float w02 = wsv[((size_t)bn * 3 + 2) * Dd + d0];
    const float w10 = wsv[((size_t)bn * 3 + 0) * Dd + d0 + 1];
    const float w11 = wsv[((size_t)bn * 3 + 1) * Dd + d0 + 1];
    const float w12 = wsv[((size_t)bn * 3 + 2) * Dd + d0 + 1];

    const unsigned short* wrow = wtp + ((size_t)b * Nn * Dd + d0) * 4;
    const unsigned short* erow = eab + (size_t)bn * Nn * Dd + d0;
    float*                orow = ipe + (size_t)bn * Nn * Dd + d0;

    const int m0 = mg * 24;
    #pragma unroll 4
    for (int m = m0; m < m0 + 24; ++m) {
        const short8 w8 = *(const short8*)(wrow + (size_t)m * Dd * 4);
        const unsigned e2 = *(const unsigned*)(erow + (size_t)m * Dd);
        const float e0 = bf2f((unsigned short)(e2 & 0xffffu));
        const float e1 = bf2f((unsigned short)(e2 >> 16));
        float2 o;
        o.x = e0 * (w00 * bf2f((unsigned short)w8[0]) + w01 * bf2f((unsigned short)w8[1])
                  + w02 * bf2f((unsigned short)w8[2]));
        o.y = e1 * (w10 * bf2f((unsigned short)w8[4]) + w11 * bf2f((unsigned short)w8[5])
                  + w12 * bf2f((unsigned short)w8[6]));
        *(float2*)(orow + (size_t)m * Dd) = o;
    }
}

extern "C" void kernel_launch(void* const* d_in, const int* in_sizes, int n_in,
                              void* d_out, int out_size, void* d_ws, size_t ws_size,
                              hipStream_t stream)
{
    const float* x    = (const float*)d_in[0];
    const float* vec  = (const float*)d_in[1];
    const float* dist = (const float*)d_in[2];
    const float* edge = (const float*)d_in[3];
    const int*   mask = (const int*)d_in[4];
    const float* Wq   = (const float*)d_in[5];
    const float* bq   = (const float*)d_in[6];
    const float* Wk   = (const float*)d_in[7];
    const float* bk   = (const float*)d_in[8];
    const float* Wv   = (const float*)d_in[9];
    const float* bv   = (const float*)d_in[10];
    const float* Wdk  = (const float*)d_in[11];
    const float* bdk  = (const float*)d_in[12];
    const float* Wdu  = (const float*)d_in[13];
    const float* bdu  = (const float*)d_in[14];
    const float* Wdih = (const float*)d_in[15];
    const float* Wea  = (const float*)d_in[16];
    const float* bea  = (const float*)d_in[17];

    float* out_attn = (float*)d_out;
    float* out_ipe  = out_attn + (size_t)BN * Dd;

    char* wsp = (char*)d_ws;
    unsigned short* eab  = (unsigned short*)wsp;  wsp += (size_t)MT * Dd * 2;
    float* qb    = (float*)wsp;                   wsp += (size_t)BN * Dd * 4;
    float* kb    = (float*)wsp;                   wsp += (size_t)BN * Dd * 4;
    float* vb    = (float*)wsp;                   wsp += (size_t)BN * Dd * 4;
    float* tpart = (float*)wsp;                   wsp += (size_t)NMB * BN * 3 * Dd * 4;
    float* apart = (float*)wsp;                   wsp += (size_t)NMB * BN * Dd * 4;
    float* wsvp  = (float*)wsp;                   wsp += (size_t)BN * 3 * Dd * 4;
    unsigned short* wtpp = (unsigned short*)wsp;  wsp += (size_t)BN * Dd * 4 * 2;
    short* Wtdk  = (short*)wsp;                   wsp += (size_t)Dd * Dd * 2;
    short* Wtea  = (short*)wsp;                   wsp += (size_t)Dd * Dd * 2;

    setup_kernel<<<WT_BLOCKS + QKV_BLOCKS, 256, 0, stream>>>(
        Wdk, Wea, Wtdk, Wtea,
        x, Wq, bq, Wk, bk, Wv, bv, qb, kb, vb);
    dk_attn_kernel<<<NMB * BN, 512, 0, stream>>>(edge, Wtdk, Wtea, bdk, bea,
                                                 qb, kb, vb, mask, dist, vec,
                                                 apart, tpart, eab);
    du_kernel<<<BN, 256, 0, stream>>>(tpart, apart, mask, vec, Wdu, bdu, Wdih,
                                      out_attn, wsvp, wtpp);
    ipe_kernel<<<BN, 512, 0, stream>>>(eab, wsvp, wtpp, out_ipe);
}

// Round 5
// 269.567 us; speedup vs baseline: 1.1462x; 1.1462x over previous
//
#include <hip/hip_runtime.h>
#include <hip/hip_bf16.h>
#include <math.h>

#define Bb 8
#define Nn 96
#define Dd 256
#define BN (Bb*Nn)      /* 768 */
#define MT (BN*Nn)      /* 73728 edge rows */
#define PI_OVER_CUTOFF 0.62831853071795864769f  /* pi/5 */

#define QKV_BLOCKS  ((BN / 2) * 3)         /* 1152, dispatched FIRST (latency-chained) */
#define WT_BLOCKS   512
#define PREP_BLOCKS (MT * Dd / (256*16))   /* 4608: 16 elts/thread streaming */

typedef short short8 __attribute__((ext_vector_type(8)));
typedef float f32x4  __attribute__((ext_vector_type(4)));

// fast silu: v_exp_f32 + v_rcp_f32 are ~1ulp; inputs already bf16-quantized.
__device__ __forceinline__ float silu_f(float x){
    return x * __builtin_amdgcn_rcpf(1.0f + __expf(-x));
}

__device__ __forceinline__ short f2bf(float f){
    __hip_bfloat16 h = __float2bfloat16(f);
    return __builtin_bit_cast(short, h);
}
__device__ __forceinline__ float bf2f(unsigned short u){
    union { unsigned uu; float ff; } a; a.uu = ((unsigned)u) << 16; return a.ff;
}

// async global->LDS, 16B per lane. LDS dest = base + lane*16 (wave-uniform base).
__device__ __forceinline__ void gll16(short* lds, const unsigned short* g){
    __builtin_amdgcn_global_load_lds(
        (const __attribute__((address_space(1))) unsigned int*)g,
        (__attribute__((address_space(3))) unsigned int*)lds, 16, 0, 0);
}

// ---------------- Kernel 1: setup = qkv (first: latency-bound) + wt + prep (stream) ----------------
__global__ __launch_bounds__(256) void setup_kernel(
    const float* __restrict__ edge, unsigned short* __restrict__ ebf,
    const float* __restrict__ Wdk, const float* __restrict__ Wea,
    short* __restrict__ Wtdk, short* __restrict__ Wtea,
    const float* __restrict__ x,
    const float* __restrict__ Wq, const float* __restrict__ bq,
    const float* __restrict__ Wk, const float* __restrict__ bk,
    const float* __restrict__ Wv, const float* __restrict__ bv,
    float* __restrict__ qo, float* __restrict__ ko, float* __restrict__ vo)
{
    const int blk = blockIdx.x;
    const int tid = threadIdx.x;

    if (blk < QKV_BLOCKS) {
        // ---- qkv: 2 rows, 1 matrix per block (long latency chain -> dispatch first) ----
        __shared__ float xs[2][Dd];
        const int idx = blk;
        const int sel = idx % 3;
        const int r0  = (idx / 3) * 2;
        const float* W  = sel == 0 ? Wq : (sel == 1 ? Wk : Wv);
        const float* bb = sel == 0 ? bq : (sel == 1 ? bk : bv);
        float*       ou = sel == 0 ? qo : (sel == 1 ? ko : vo);

        #pragma unroll
        for (int i = 0; i < 2; ++i) xs[i][tid] = x[(size_t)(r0 + i) * Dd + tid];
        __syncthreads();

        float a0, a1;
        a0 = a1 = bb[tid];
        for (int k4 = 0; k4 < 64; ++k4) {
            const float w0 = W[(size_t)(k4 * 4 + 0) * Dd + tid];
            const float w1 = W[(size_t)(k4 * 4 + 1) * Dd + tid];
            const float w2 = W[(size_t)(k4 * 4 + 2) * Dd + tid];
            const float w3 = W[(size_t)(k4 * 4 + 3) * Dd + tid];
            const float4 e0 = *(const float4*)&xs[0][k4 * 4];
            const float4 e1 = *(const float4*)&xs[1][k4 * 4];
            a0 = fmaf(e0.x, w0, fmaf(e0.y, w1, fmaf(e0.z, w2, fmaf(e0.w, w3, a0))));
            a1 = fmaf(e1.x, w0, fmaf(e1.y, w1, fmaf(e1.z, w2, fmaf(e1.w, w3, a1))));
        }
        ou[(size_t)r0 * Dd + tid]       = a0;
        ou[(size_t)(r0 + 1) * Dd + tid] = a1;
        return;
    }
    if (blk < QKV_BLOCKS + WT_BLOCKS) {
        // ---- Wt = bf16(W^T): coalesced READ, scattered 2B write (fire-and-forget) ----
        const int o   = (blk - QKV_BLOCKS) * 256 + tid;
        const int sel = o >> 16;
        const int r   = o & 65535;           // r = k*256 + n (source-linear)
        const float* src = sel ? Wea : Wdk;
        short*       dst = sel ? Wtea : Wtdk;
        dst[(r & 255) * 256 + (r >> 8)] = f2bf(src[r]);
        return;
    }

    // ---- prep: edge fp32 -> bf16, 16 elts/thread (4 independent float4 loads) ----
    const size_t idx = ((size_t)(blk - QKV_BLOCKS - WT_BLOCKS) * 256 + tid) * 16;
    const float4 a = *(const float4*)(edge + idx);
    const float4 b = *(const float4*)(edge + idx + 4);
    const float4 c = *(const float4*)(edge + idx + 8);
    const float4 d = *(const float4*)(edge + idx + 12);
    short8 s0, s1;
    s0[0]=f2bf(a.x); s0[1]=f2bf(a.y); s0[2]=f2bf(a.z); s0[3]=f2bf(a.w);
    s0[4]=f2bf(b.x); s0[5]=f2bf(b.y); s0[6]=f2bf(b.z); s0[7]=f2bf(b.w);
    s1[0]=f2bf(c.x); s1[1]=f2bf(c.y); s1[2]=f2bf(c.z); s1[3]=f2bf(c.w);
    s1[4]=f2bf(d.x); s1[5]=f2bf(d.y); s1[6]=f2bf(d.z); s1[7]=f2bf(d.w);
    *(short8*)(ebf + idx)     = s0;
    *(short8*)(ebf + idx + 8) = s1;
}

// ---------------- Kernel 2: fused dk-GEMM (MFMA, async staged) + attention ----------------
// 512 thr = 8 waves; wave w owns cols [w*32,+32) = head w. 96 rows (m), K=256 staged
// in one shot (both 128-chunks in LDS via global_load_lds, single barrier).
__global__ __launch_bounds__(512, 4) void dk_attn_kernel(
    const unsigned short* __restrict__ ebf, const short* __restrict__ Wt,
    const float* __restrict__ bdk,
    const float* __restrict__ q, const float* __restrict__ kmat, const float* __restrict__ vmat,
    const int* __restrict__ mask, const float* __restrict__ dist, const float* __restrict__ vec,
    float* __restrict__ attn_out, float* __restrict__ t_out, float* __restrict__ sv_out)
{
    __shared__ short As[2 * 96 * 128];   // 48 KB, both K-chunks resident
    __shared__ float scl[Nn];
    __shared__ float vcs[Nn][3];
    __shared__ int   mks[Nn];

    const int bn   = blockIdx.x;
    const int b    = bn / Nn;
    const int tid  = threadIdx.x;
    const int lane = tid & 63;
    const int w    = tid >> 6;
    const int l15  = lane & 15;
    const int lq   = lane >> 4;

    if (tid < Nn) {
        const int   mm = mask[(size_t)bn * Nn + tid];
        const float di = dist[(size_t)bn * Nn + tid];
        const float s  = (di < 5.0f) ? 0.5f * (__cosf(di * PI_OVER_CUTOFF) + 1.0f) : 0.0f;
        scl[tid] = mm ? 0.0f : s;
        mks[tid] = mm;
    }
    for (int j = tid; j < Nn * 3; j += 512)
        (&vcs[0][0])[j] = vec[(size_t)bn * Nn * 3 + j];

    const int dj0 = w * 32 + l15, dj1 = dj0 + 16;
    const float qd0 = q[(size_t)bn * Dd + dj0], qd1 = q[(size_t)bn * Dd + dj1];
    const float bv0 = bdk[dj0], bv1 = bdk[dj1];

    f32x4 acc[6][2];
    #pragma unroll
    for (int i = 0; i < 6; ++i) { acc[i][0] = (f32x4){0.f,0.f,0.f,0.f}; acc[i][1] = (f32x4){0.f,0.f,0.f,0.f}; }

    const unsigned short* ebase = ebf + (size_t)bn * Nn * Dd;
    const int srow = (lane >> 4);          // 0..3 within chunk
    const int cs   = lane & 15;            // stored segment

    // stage BOTH K-chunks, then one barrier
    #pragma unroll
    for (int kt = 0; kt < 2; ++kt) {
        #pragma unroll
        for (int u = 0; u < 3; ++u) {
            const int chunk = w * 3 + u;           // 0..23, 4 rows each
            const int r     = chunk * 4 + srow;
            const int gseg  = cs ^ (r & 7);
            gll16(As + kt * (96*128) + chunk * 512,
                  ebase + (size_t)r * Dd + kt * 128 + gseg * 8);
        }
    }
    __syncthreads();

    #pragma unroll
    for (int kt = 0; kt < 2; ++kt) {
        short8 bf[2][4];
        #pragma unroll
        for (int s = 0; s < 4; ++s) {
            bf[0][s] = *(const short8*)(Wt + (size_t)dj0 * 256 + kt * 128 + s * 32 + lq * 8);
            bf[1][s] = *(const short8*)(Wt + (size_t)dj1 * 256 + kt * 128 + s * 32 + lq * 8);
        }
        #pragma unroll
        for (int i = 0; i < 6; ++i) {
            const int row = i * 16 + l15;
            const int rx  = row & 7;
            #pragma unroll
            for (int s = 0; s < 4; ++s) {
                const int pos = (s * 4 + lq) ^ rx;
                const short8 af = *(const short8*)&As[kt * (96*128) + row * 128 + pos * 8];
                acc[i][0] = __builtin_amdgcn_mfma_f32_16x16x32_bf16(af, bf[0][s], acc[i][0], 0, 0, 0);
                acc[i][1] = __builtin_amdgcn_mfma_f32_16x16x32_bf16(af, bf[1][s], acc[i][1], 0, 0, 0);
            }
        }
    }

    float attn0 = 0.f, attn1 = 0.f;
    float t00=0.f, t01=0.f, t02=0.f, t10=0.f, t11=0.f, t12=0.f;

    #pragma unroll
    for (int i = 0; i < 6; ++i) {
        #pragma unroll
        for (int rr = 0; rr < 4; ++rr) {
            const int m = i * 16 + lq * 4 + rr;
            const size_t krow = ((size_t)(b * Nn + m)) << 8;
            const float k0 = kmat[krow + dj0], k1 = kmat[krow + dj1];
            const float v0 = vmat[krow + dj0], v1 = vmat[krow + dj1];
            float pr = silu_f(acc[i][0][rr] + bv0) * k0 * qd0
                     + silu_f(acc[i][1][rr] + bv1) * k1 * qd1;
            #pragma unroll
            for (int off = 8; off; off >>= 1)
                pr += __shfl_xor(pr, off, 16);
            const float p = silu_f(pr) * scl[m];
            const float pv0 = p * v0, pv1 = p * v1;
            attn0 += pv0; attn1 += pv1;
            const float c0 = vcs[m][0], c1 = vcs[m][1], c2 = vcs[m][2];
            t00 = fmaf(c0, pv0, t00); t01 = fmaf(c1, pv0, t01); t02 = fmaf(c2, pv0, t02);
            t10 = fmaf(c0, pv1, t10); t11 = fmaf(c1, pv1, t11); t12 = fmaf(c2, pv1, t12);
        }
    }

    attn0 += __shfl_xor(attn0, 16, 64); attn0 += __shfl_xor(attn0, 32, 64);
    attn1 += __shfl_xor(attn1, 16, 64); attn1 += __shfl_xor(attn1, 32, 64);
    t00 += __shfl_xor(t00, 16, 64); t00 += __shfl_xor(t00, 32, 64);
    t01 += __shfl_xor(t01, 16, 64); t01 += __shfl_xor(t01, 32, 64);
    t02 += __shfl_xor(t02, 16, 64); t02 += __shfl_xor(t02, 32, 64);
    t10 += __shfl_xor(t10, 16, 64); t10 += __shfl_xor(t10, 32, 64);
    t11 += __shfl_xor(t11, 16, 64); t11 += __shfl_xor(t11, 32, 64);
    t12 += __shfl_xor(t12, 16, 64); t12 += __shfl_xor(t12, 32, 64);

    if (lq == 0) {
        attn_out[(size_t)bn * Dd + dj0] = attn0;
        attn_out[(size_t)bn * Dd + dj1] = attn1;
        t_out[((size_t)bn * 3 + 0) * Dd + dj0] = t00;
        t_out[((size_t)bn * 3 + 1) * Dd + dj0] = t01;
        t_out[((size_t)bn * 3 + 2) * Dd + dj0] = t02;
        t_out[((size_t)bn * 3 + 0) * Dd + dj1] = t10;
        t_out[((size_t)bn * 3 + 1) * Dd + dj1] = t11;
        t_out[((size_t)bn * 3 + 2) * Dd + dj1] = t12;
    }
    // wave-parallel sum of vec over unmasked m (3 waves, one per component)
    if (tid < 192) {
        const int c  = tid >> 6;
        const int ln = tid & 63;
        float s = 0.0f;
        for (int m = ln; m < Nn; m += 64)
            if (!mks[m]) s += vcs[m][c];
        #pragma unroll
        for (int off = 32; off; off >>= 1) s += __shfl_xor(s, off, 64);
        if (ln == 0) sv_out[(size_t)bn * 3 + c] = s;
    }
}

// ---------------- Kernel 3: du = t@Wdu + svec*bdu ; w = du@Wdih -> ws(f32), wt(bf16 packed) ----
__global__ __launch_bounds__(256) void du_kernel(
    const float* __restrict__ t_in, const float* __restrict__ sv_in,
    const float* __restrict__ Wdu, const float* __restrict__ bdu,
    const float* __restrict__ Wdih,
    float* __restrict__ wsv, unsigned short* __restrict__ wtp)
{
    const int bn  = blockIdx.x;
    const int tid = threadIdx.x;
    __shared__ float ts[3][Dd];
    __shared__ float dus[3][Dd];

    #pragma unroll
    for (int j = 0; j < 3; ++j)
        ts[j][tid] = t_in[((size_t)bn * 3 + j) * Dd + tid];
    __syncthreads();

    float du[3];
    const float bd = bdu[tid];
    #pragma unroll
    for (int j = 0; j < 3; ++j) du[j] = sv_in[(size_t)bn * 3 + j] * bd;

    for (int k4 = 0; k4 < 64; ++k4) {
        const float w0 = Wdu[(size_t)(k4 * 4 + 0) * Dd + tid];
        const float w1 = Wdu[(size_t)(k4 * 4 + 1) * Dd + tid];
        const float w2 = Wdu[(size_t)(k4 * 4 + 2) * Dd + tid];
        const float w3 = Wdu[(size_t)(k4 * 4 + 3) * Dd + tid];
        #pragma unroll
        for (int j = 0; j < 3; ++j) {
            const float4 e = *(const float4*)&ts[j][k4 * 4];
            du[j] = fmaf(e.x, w0, fmaf(e.y, w1, fmaf(e.z, w2, fmaf(e.w, w3, du[j]))));
        }
    }
    #pragma unroll
    for (int j = 0; j < 3; ++j) dus[j][tid] = du[j];
    __syncthreads();

    float as[3] = {0.f, 0.f, 0.f}, at[3] = {0.f, 0.f, 0.f};

    for (int k4 = 0; k4 < 64; ++k4) {
        const float s0 = Wdih[(size_t)(k4 * 4 + 0) * 512 + tid];
        const float s1 = Wdih[(size_t)(k4 * 4 + 1) * 512 + tid];
        const float s2 = Wdih[(size_t)(k4 * 4 + 2) * 512 + tid];
        const float s3 = Wdih[(size_t)(k4 * 4 + 3) * 512 + tid];
        const float u0 = Wdih[(size_t)(k4 * 4 + 0) * 512 + 256 + tid];
        const float u1 = Wdih[(size_t)(k4 * 4 + 1) * 512 + 256 + tid];
        const float u2 = Wdih[(size_t)(k4 * 4 + 2) * 512 + 256 + tid];
        const float u3 = Wdih[(size_t)(k4 * 4 + 3) * 512 + 256 + tid];
        #pragma unroll
        for (int j = 0; j < 3; ++j) {
            const float4 e = *(const float4*)&dus[j][k4 * 4];
            as[j] = fmaf(e.x, s0, fmaf(e.y, s1, fmaf(e.z, s2, fmaf(e.w, s3, as[j]))));
            at[j] = fmaf(e.x, u0, fmaf(e.y, u1, fmaf(e.z, u2, fmaf(e.w, u3, at[j]))));
        }
    }
    #pragma unroll
    for (int j = 0; j < 3; ++j)
        wsv[((size_t)bn * 3 + j) * Dd + tid] = as[j];
    ushort4 pk;
    pk.x = (unsigned short)f2bf(at[0]);
    pk.y = (unsigned short)f2bf(at[1]);
    pk.z = (unsigned short)f2bf(at[2]);
    pk.w = 0;
    *(ushort4*)(wtp + ((size_t)bn * Dd + tid) * 4) = pk;
}

// ---------------- Kernel 4: ipe = silu(edge@Wea + bea) * sum_c ws.wt (async-staged MFMA) ----------------
__global__ __launch_bounds__(512, 4) void ea_ipe_kernel(
    const unsigned short* __restrict__ ebf, const short* __restrict__ Wt,
    const float* __restrict__ bea,
    const float* __restrict__ wsv, const unsigned short* __restrict__ wtp,
    float* __restrict__ ipe)
{
    __shared__ short As[2 * 96 * 128];
    const int bn   = blockIdx.x;
    const int b    = bn / Nn;
    const int tid  = threadIdx.x;
    const int lane = tid & 63;
    const int w    = tid >> 6;
    const int l15  = lane & 15;
    const int lq   = lane >> 4;

    const int dj0 = w * 32 + l15, dj1 = dj0 + 16;
    const float be0 = bea[dj0], be1 = bea[dj1];
    const float ws00 = wsv[((size_t)bn*3+0)*Dd + dj0], ws01 = wsv[((size_t)bn*3+1)*Dd + dj0],
                ws02 = wsv[((size_t)bn*3+2)*Dd + dj0];
    const float ws10 = wsv[((size_t)bn*3+0)*Dd + dj1], ws11 = wsv[((size_t)bn*3+1)*Dd + dj1],
                ws12 = wsv[((size_t)bn*3+2)*Dd + dj1];

    f32x4 acc[6][2];
    #pragma unroll
    for (int i = 0; i < 6; ++i) { acc[i][0] = (f32x4){0.f,0.f,0.f,0.f}; acc[i][1] = (f32x4){0.f,0.f,0.f,0.f}; }

    const unsigned short* ebase = ebf + (size_t)bn * Nn * Dd;
    const int srow = (lane >> 4);
    const int cs   = lane & 15;

    #pragma unroll
    for (int kt = 0; kt < 2; ++kt) {
        #pragma unroll
        for (int u = 0; u < 3; ++u) {
            const int chunk = w * 3 + u;
            const int r     = chunk * 4 + srow;
            const int gseg  = cs ^ (r & 7);
            gll16(As + kt * (96*128) + chunk * 512,
                  ebase + (size_t)r * Dd + kt * 128 + gseg * 8);
        }
    }
    __syncthreads();

    #pragma unroll
    for (int kt = 0; kt < 2; ++kt) {
        short8 bf[2][4];
        #pragma unroll
        for (int s = 0; s < 4; ++s) {
            bf[0][s] = *(const short8*)(Wt + (size_t)dj0 * 256 + kt * 128 + s * 32 + lq * 8);
            bf[1][s] = *(const short8*)(Wt + (size_t)dj1 * 256 + kt * 128 + s * 32 + lq * 8);
        }
        #pragma unroll
        for (int i = 0; i < 6; ++i) {
            const int row = i * 16 + l15;
            const int rx  = row & 7;
            #pragma unroll
            for (int s = 0; s < 4; ++s) {
                const int pos = (s * 4 + lq) ^ rx;
                const short8 af = *(const short8*)&As[kt * (96*128) + row * 128 + pos * 8];
                acc[i][0] = __builtin_amdgcn_mfma_f32_16x16x32_bf16(af, bf[0][s], acc[i][0], 0, 0, 0);
                acc[i][1] = __builtin_amdgcn_mfma_f32_16x16x32_bf16(af, bf[1][s], acc[i][1], 0, 0, 0);
            }
        }
    }

    #pragma unroll
    for (int i = 0; i < 6; ++i) {
        #pragma unroll
        for (int rr = 0; rr < 4; ++rr) {
            const int m = i * 16 + lq * 4 + rr;
            const size_t wr = (size_t)(b * Nn + m);
            const ushort4 w40 = *(const ushort4*)(wtp + (wr * Dd + dj0) * 4);
            const ushort4 w41 = *(const ushort4*)(wtp + (wr * Dd + dj1) * 4);
            const float ea0 = silu_f(acc[i][0][rr] + be0);
            const float ea1 = silu_f(acc[i][1][rr] + be1);
            const float sd0 = ws00 * bf2f(w40.x) + ws01 * bf2f(w40.y) + ws02 * bf2f(w40.z);
            const float sd1 = ws10 * bf2f(w41.x) + ws11 * bf2f(w41.y) + ws12 * bf2f(w41.z);
            ipe[((size_t)bn * Nn + m) * Dd + dj0] = ea0 * sd0;
            ipe[((size_t)bn * Nn + m) * Dd + dj1] = ea1 * sd1;
        }
    }
}

extern "C" void kernel_launch(void* const* d_in, const int* in_sizes, int n_in,
                              void* d_out, int out_size, void* d_ws, size_t ws_size,
                              hipStream_t stream)
{
    const float* x    = (const float*)d_in[0];
    const float* vec  = (const float*)d_in[1];
    const float* dist = (const float*)d_in[2];
    const float* edge = (const float*)d_in[3];
    const int*   mask = (const int*)d_in[4];
    const float* Wq   = (const float*)d_in[5];
    const float* bq   = (const float*)d_in[6];
    const float* Wk   = (const float*)d_in[7];
    const float* bk   = (const float*)d_in[8];
    const float* Wv   = (const float*)d_in[9];
    const float* bv   = (const float*)d_in[10];
    const float* Wdk  = (const float*)d_in[11];
    const float* bdk  = (const float*)d_in[12];
    const float* Wdu  = (const float*)d_in[13];
    const float* bdu  = (const float*)d_in[14];
    const float* Wdih = (const float*)d_in[15];
    const float* Wea  = (const float*)d_in[16];
    const float* bea  = (const float*)d_in[17];

    float* out_attn = (float*)d_out;
    float* out_ipe  = out_attn + (size_t)BN * Dd;

    char* wsp = (char*)d_ws;
    unsigned short* ebf  = (unsigned short*)wsp;  wsp += (size_t)MT * Dd * 2;
    float* qb   = (float*)wsp;                    wsp += (size_t)BN * Dd * 4;
    float* kb   = (float*)wsp;                    wsp += (size_t)BN * Dd * 4;
    float* vb   = (float*)wsp;                    wsp += (size_t)BN * Dd * 4;
    float* tb   = (float*)wsp;                    wsp += (size_t)BN * 3 * Dd * 4;
    float* svb  = (float*)wsp;                    wsp += (size_t)BN * 4 * 4;
    float* wsvp = (float*)wsp;                    wsp += (size_t)BN * 3 * Dd * 4;
    unsigned short* wtpp = (unsigned short*)wsp;  wsp += (size_t)BN * Dd * 4 * 2;
    short* Wtdk = (short*)wsp;                    wsp += (size_t)Dd * Dd * 2;
    short* Wtea = (short*)wsp;                    wsp += (size_t)Dd * Dd * 2;

    setup_kernel<<<QKV_BLOCKS + WT_BLOCKS + PREP_BLOCKS, 256, 0, stream>>>(
        edge, ebf, Wdk, Wea, Wtdk, Wtea,
        x, Wq, bq, Wk, bk, Wv, bv, qb, kb, vb);
    dk_attn_kernel<<<BN, 512, 0, stream>>>(ebf, Wtdk, bdk, qb, kb, vb, mask, dist, vec,
                                           out_attn, tb, svb);
    du_kernel<<<BN, 256, 0, stream>>>(tb, svb, Wdu, bdu, Wdih, wsvp, wtpp);
    ea_ipe_kernel<<<BN, 512, 0, stream>>>(ebf, Wtea, bea, wsvp, wtpp, out_ipe);
}